// Round 1
// baseline (256.734 us; speedup 1.0000x reference)
//
#include <hip/hip_runtime.h>

#define BATCH 8
#define CIN   64
#define COUT  64
#define LEN   16384
#define KS    5
#define PADW  2
#define LP    (LEN + 2*PADW)
#define TT    32            // t-tile per block
#define CK    (CIN*KS)      // 320

__global__ __launch_bounds__(256, 2) void deform_conv1d_kernel(
    const float* __restrict__ x, const float* __restrict__ offs,
    const float* __restrict__ w, const float* __restrict__ bias,
    float* __restrict__ out)
{
    __shared__ float v[CK][TT];       // 40 KB, transposed: v[ck][t]
    __shared__ float wl[64][64];      // 16 KB W tile
    __shared__ int   i0s[KS][TT];
    __shared__ float frs[KS][TT];

    const int tid = threadIdx.x;
    const int bt  = blockIdx.x;
    const int b   = bt >> 9;               // 512 tiles per batch
    const int t0  = (bt & 511) * TT;

    // ---- Phase A: offsets -> (i0, frac) for 5*32 (k,t) pairs ----
    if (tid < KS*TT) {
        int k = tid / TT, ts = tid % TT;
        int t = t0 + ts;
        float off = offs[(b * LEN + t) * KS + k];
        float T = (float)(t + k) + off;
        T = fminf(fmaxf(T, 0.0f), (float)(LP - 1));
        int i0 = (int)floorf(T);
        if (i0 > LP - 2) i0 = LP - 2;
        if (i0 < 0) i0 = 0;
        i0s[k][ts] = i0;
        frs[k][ts] = T - (float)i0;
    }
    __syncthreads();

    // ---- Phase B: gather + lerp into v[ck][t] ----
    {
        const int ts = tid & (TT-1);
        const int pr = tid >> 5;           // 8 (c,k) pairs in flight
        for (int pp = pr; pp < CK; pp += 8) {
            int c = pp / KS, k = pp - c*KS;
            int i0 = i0s[k][ts];
            float f = frs[k][ts];
            int i1 = i0 + 1;
            // reflect map xp index -> x index (PAD=2): i<2 -> 2-i ; i>=L+2 -> 2L-i
            int j0 = (i0 < PADW) ? (PADW - i0) : ((i0 < LEN+PADW) ? (i0 - PADW) : (2*LEN - i0));
            int j1 = (i1 < PADW) ? (PADW - i1) : ((i1 < LEN+PADW) ? (i1 - PADW) : (2*LEN - i1));
            const float* xb = x + ((size_t)b * CIN + c) * LEN;
            float g0 = xb[j0], g1 = xb[j1];
            v[pp][ts] = g0 * (1.0f - f) + g1 * f;
        }
    }

    // ---- Phase 2: Out(64 x 32) = W(64 x 320) * v(320 x 32) ----
    const int ts = tid & (TT-1);
    const int og = tid >> 5;               // 0..7, thread owns o = og*8+j
    float acc[8];
    #pragma unroll
    for (int j = 0; j < 8; ++j) acc[j] = 0.0f;

    for (int ckt = 0; ckt < CK/64; ++ckt) {    // 5 tiles of 64 ck
        __syncthreads();                        // previous wl consumed
        #pragma unroll
        for (int e = tid*4; e < 4096; e += 1024) {
            int row = e >> 6, col = e & 63;
            *(float4*)&wl[row][col] = *(const float4*)&w[row*CK + ckt*64 + col];
        }
        __syncthreads();
        #pragma unroll
        for (int q4 = 0; q4 < 16; ++q4) {
            float v0 = v[ckt*64 + q4*4 + 0][ts];
            float v1 = v[ckt*64 + q4*4 + 1][ts];
            float v2 = v[ckt*64 + q4*4 + 2][ts];
            float v3 = v[ckt*64 + q4*4 + 3][ts];
            #pragma unroll
            for (int j = 0; j < 8; ++j) {
                float4 wv = *(float4*)&wl[og*8 + j][q4*4];
                acc[j] = fmaf(wv.x, v0, acc[j]);
                acc[j] = fmaf(wv.y, v1, acc[j]);
                acc[j] = fmaf(wv.z, v2, acc[j]);
                acc[j] = fmaf(wv.w, v3, acc[j]);
            }
        }
    }

    // ---- Store + bias ----
    #pragma unroll
    for (int j = 0; j < 8; ++j) {
        int o = og*8 + j;
        out[((size_t)(b*COUT + o)) * LEN + t0 + ts] = acc[j] + bias[o];
    }
}

extern "C" void kernel_launch(void* const* d_in, const int* in_sizes, int n_in,
                              void* d_out, int out_size, void* d_ws, size_t ws_size,
                              hipStream_t stream) {
    const float* x    = (const float*)d_in[0];
    const float* offs = (const float*)d_in[1];
    const float* w    = (const float*)d_in[2];
    const float* bias = (const float*)d_in[3];
    float* out = (float*)d_out;

    dim3 grid(BATCH * (LEN / TT));   // 4096 blocks
    deform_conv1d_kernel<<<grid, 256, 0, stream>>>(x, offs, w, bias, out);
}

// Round 2
// 62.463 us; speedup vs baseline: 4.1102x; 4.1102x over previous
//
#include <hip/hip_runtime.h>

#define BATCH 8
#define CIN   64
#define COUT  64
#define LEN   16384
#define KS    5
#define PADW  2
#define LP    (LEN + 2*PADW)
#define TT    64
#define NK8   40            // 16B chunks along K (320 bf16 * 2B / 16B)

typedef __attribute__((ext_vector_type(8)))  short  short8;
typedef __attribute__((ext_vector_type(16))) float  f32x16;
typedef __attribute__((ext_vector_type(8)))  unsigned short ushort8;

__device__ __forceinline__ unsigned short bf16r(float f) {
    unsigned u = __builtin_bit_cast(unsigned, f);
    u += 0x7FFF + ((u >> 16) & 1);          // RNE
    return (unsigned short)(u >> 16);
}

// Pre-arrange W (f32 [o][c][k]) into bf16 A-fragment order for
// mfma_f32_32x32x16_bf16, K-dim reordered k-major: ck' = k*64 + c.
// Layout: wf[((wm*20 + kk)*64 + lane)*8 + bidx]
//   A[row][kq]: row = lane%32, kq = (lane/32)*8 + bidx, global k-index = kk*16 + kq
__global__ void wfrag_kernel(const float* __restrict__ w, unsigned short* __restrict__ wf) {
    int el = blockIdx.x * 256 + threadIdx.x;     // 20480 total
    int bidx = el & 7;
    int lane = (el >> 3) & 63;
    int kk   = (el >> 9) % 20;
    int wm   = el / 10240;
    int o    = wm * 32 + (lane & 31);
    int ckp  = kk * 16 + ((lane >> 5) << 3) + bidx;   // 0..319, k-major
    int k    = ckp >> 6;                              // /64
    int c    = ckp & 63;
    wf[el] = bf16r(w[(o * 64 + c) * 5 + k]);
}

__global__ __launch_bounds__(256) void deform_mfma_kernel(
    const float* __restrict__ x, const float* __restrict__ offs,
    const unsigned short* __restrict__ wf, const float* __restrict__ bias,
    float* __restrict__ out)
{
    __shared__ __align__(16) unsigned short vlds[NK8 * 64 * 8];   // 40 KB, [k8][t][8]

    const int tid = threadIdx.x;
    const int bt  = blockIdx.x;
    const int b   = bt >> 8;                 // 256 t-tiles per batch
    const int t0  = (bt & 255) * TT;
    const int tl  = tid & 63;
    const int w   = tid >> 6;                // wave 0..3
    const int t   = t0 + tl;

    // ---- per-thread (j0, j1, frac) for k = 0..4 (compile-time indexed -> registers) ----
    int j0r[KS], j1r[KS]; float frr[KS];
    #pragma unroll
    for (int k = 0; k < KS; ++k) {
        float off = offs[(size_t)(b * LEN + t) * KS + k];
        float T = (float)(t + k) + off;
        T = fminf(fmaxf(T, 0.0f), (float)(LP - 1));
        int i0 = (int)floorf(T);
        i0 = min(i0, LP - 2); i0 = max(i0, 0);
        frr[k] = T - (float)i0;
        int i1 = i0 + 1;
        j0r[k] = (i0 < PADW) ? (PADW - i0) : ((i0 < LEN + PADW) ? (i0 - PADW) : (2*LEN - i0));
        j1r[k] = (i1 < PADW) ? (PADW - i1) : ((i1 < LEN + PADW) ? (i1 - PADW) : (2*LEN - i1));
    }

    // ---- gather + lerp + bf16 pack into LDS: v[ck'=k*64+c][t] as 16B chunks [k8][t] ----
    // wave handles k8 = w + 4*it; k = k8>>3 == it>>1 (compile-time); c0 = (k8&7)*8
    const float* xb0 = x + (size_t)b * CIN * LEN;
    #pragma unroll
    for (int it = 0; it < 10; ++it) {
        const int k  = it >> 1;                        // compile-time
        const int c0 = (w + ((it & 1) << 2)) << 3;     // (w + 4*(it&1)) * 8
        const int j0 = j0r[k], j1 = j1r[k];
        const float f = frr[k];
        ushort8 pk;
        const float* xc = xb0 + (size_t)c0 * LEN;
        #pragma unroll
        for (int e = 0; e < 8; ++e) {
            float g0 = xc[j0];
            float g1 = xc[j1];
            pk[e] = bf16r(fmaf(f, g1 - g0, g0));
            xc += LEN;
        }
        const int k8 = w + (it << 2);
        *(ushort8*)&vlds[(k8 * 64 + tl) * 8] = pk;
    }
    __syncthreads();

    // ---- MFMA: out[64cout x 64t] via 4 waves, each one 32x32 tile, K=320 ----
    const int lane = tid & 63;
    const int wm = w >> 1, wn = w & 1;
    f32x16 acc = {};
    const unsigned short* wfp = wf + ((size_t)(wm * 20) * 64 + lane) * 8;
    const int boff = (((lane >> 5) * 64) + wn * 32 + (lane & 31)) * 8;
    #pragma unroll
    for (int kk = 0; kk < 20; ++kk) {
        short8 a  = *(const short8*)&wfp[kk * 512];            // A-frag, linear per lane
        short8 bf = *(const short8*)&vlds[boff + kk * 1024];   // B-frag, lane-linear
        acc = __builtin_amdgcn_mfma_f32_32x32x16_bf16(a, bf, acc, 0, 0, 0);
    }

    // ---- epilogue: C/D layout col=lane&31, row=(reg&3)+8*(reg>>2)+4*(lane>>5) ----
    const int tc = t0 + wn * 32 + (lane & 31);
    const int rbase = 4 * (lane >> 5);
    #pragma unroll
    for (int r = 0; r < 16; ++r) {
        int row = (r & 3) + 8 * (r >> 2) + rbase;
        int o = wm * 32 + row;
        out[((size_t)(b * COUT + o)) * LEN + tc] = acc[r] + bias[o];
    }
}

extern "C" void kernel_launch(void* const* d_in, const int* in_sizes, int n_in,
                              void* d_out, int out_size, void* d_ws, size_t ws_size,
                              hipStream_t stream) {
    const float* x    = (const float*)d_in[0];
    const float* offs = (const float*)d_in[1];
    const float* w    = (const float*)d_in[2];
    const float* bias = (const float*)d_in[3];
    float* out = (float*)d_out;
    unsigned short* wf = (unsigned short*)d_ws;   // 40960 B needed

    wfrag_kernel<<<80, 256, 0, stream>>>(w, wf);
    deform_mfma_kernel<<<BATCH * (LEN / TT), 256, 0, stream>>>(x, offs, wf, bias, out);
}